// Round 6
// baseline (2600.574 us; speedup 1.0000x reference)
//
#include <hip/hip_runtime.h>
#include <hip/hip_bf16.h>

namespace {

constexpr int kB = 32;
constexpr int kT = 512;
constexpr int kH = 512;
constexpr int kE = 256;
constexpr int kL = 64;
constexpr int kNC = 7 * kH;       // 3584 gate columns
constexpr int kOutRow = 5 * kH;   // 2560
constexpr int kBH = kB * kH;      // 16384 elements per parity slot

typedef float f32x4 __attribute__((ext_vector_type(4)));
typedef short s16x8 __attribute__((ext_vector_type(8)));
typedef __bf16 bf16x8 __attribute__((ext_vector_type(8)));
typedef unsigned int u32x4 __attribute__((ext_vector_type(4)));
typedef unsigned int u32x2 __attribute__((ext_vector_type(2)));

__device__ __forceinline__ unsigned short f2bf(float f) {
  __hip_bfloat16 h = __float2bfloat16(f);
  return __builtin_bit_cast(unsigned short, h);
}

__device__ __forceinline__ float bf2f(unsigned short u) {
  return __builtin_bit_cast(float, (unsigned int)u << 16);
}

// libm versions (setup only)
__device__ __forceinline__ float sigmoid_f(float x) {
  return 1.0f / (1.0f + expf(-x));
}
__device__ __forceinline__ float softplus_f(float x) {
  return fmaxf(x, 0.0f) + log1pf(expf(-fabsf(x)));
}

// fast versions (hot kernel)
constexpr float kLog2e = 1.4426950408889634f;
constexpr float kLn2 = 0.6931471805599453f;
__device__ __forceinline__ float fexp2(float x) {
  return __builtin_amdgcn_exp2f(x);
}
__device__ __forceinline__ float frcp(float x) {
  return __builtin_amdgcn_rcpf(x);
}
__device__ __forceinline__ float fsigmoid(float x) {
  return frcp(1.0f + fexp2(-x * kLog2e));
}
__device__ __forceinline__ float ftanh(float x) {
  return 1.0f - 2.0f * frcp(1.0f + fexp2((2.0f * kLog2e) * x));
}
__device__ __forceinline__ float fsoftplus(float x) {
  return fmaxf(x, 0.0f) +
         kLn2 * __builtin_amdgcn_logf(1.0f + fexp2(-fabsf(x) * kLog2e));
}

__device__ __forceinline__ f32x4 mfma_bf16(s16x8 a, s16x8 b, f32x4 c) {
  return __builtin_amdgcn_mfma_f32_16x16x32_bf16(
      __builtin_bit_cast(bf16x8, a), __builtin_bit_cast(bf16x8, b), c, 0, 0, 0);
}

__device__ __forceinline__ int ldflag(const int* p) {
  int v;
  asm volatile("global_load_dword %0, %1, off sc0 sc1\n\ts_waitcnt vmcnt(0)"
               : "=v"(v) : "v"(p) : "memory");
  return v;
}

__device__ __forceinline__ void st_coh_u32(unsigned int* p, unsigned int v) {
  asm volatile("global_store_dword %0, %1, off sc0 sc1" :: "v"(p), "v"(v)
               : "memory");
}

__device__ __forceinline__ void st_coh_x2(unsigned int* p, u32x2 v) {
  asm volatile("global_store_dwordx2 %0, %1, off sc0 sc1" :: "v"(p), "v"(v)
               : "memory");
}

__device__ __forceinline__ void unpack(const u32x4& x0, const u32x4& x1,
                                       s16x8& hi, s16x8& lo) {
#pragma unroll
  for (int e = 0; e < 4; ++e) {
    hi[e] = (short)(x0[e] & 0xffffu);
    hi[e + 4] = (short)(x1[e] & 0xffffu);
    lo[e] = (short)(x0[e] >> 16);
    lo[e + 4] = (short)(x1[e] >> 16);
  }
}

// ---------------------------------------------------------------------------
// Setup: emb_part [128][3584], lat_part(+bias) [32][3584], dt [32][512],
// init states -> out row 0, hdtag parity0 = {h0, tag 0}, parity1 poisoned,
// flags = 0.
// ---------------------------------------------------------------------------
__global__ void hawkes_setup(const float* __restrict__ ts,
                             const float* __restrict__ latent,
                             const float* __restrict__ emb,
                             const float* __restrict__ Wc,
                             const float* __restrict__ bc,
                             const float* __restrict__ Wi,
                             const float* __restrict__ bi,
                             float* __restrict__ out,
                             float* __restrict__ emb_part,
                             float* __restrict__ lat_part,
                             float* __restrict__ dt,
                             float* __restrict__ cd0,
                             float* __restrict__ cb0,
                             unsigned int* __restrict__ hdtag,
                             int* __restrict__ flags) {
  const int blk = blockIdx.x;
  const int tid = threadIdx.x;
  if (blk < 112) {
    __shared__ float es[16][kE];
    const int cgrp = blk / 14;
    const int col = (blk % 14) * 256 + tid;
    for (int i = tid; i < 16 * kE; i += 256)
      es[i / kE][i % kE] = emb[(cgrp * 16 + i / kE) * kE + (i % kE)];
    __syncthreads();
    float acc[16];
#pragma unroll
    for (int c = 0; c < 16; ++c) acc[c] = 0.0f;
    for (int e = 0; e < kE; ++e) {
      const float w = Wc[(size_t)e * kNC + col];
#pragma unroll
      for (int c = 0; c < 16; ++c) acc[c] = fmaf(es[c][e], w, acc[c]);
    }
#pragma unroll
    for (int c = 0; c < 16; ++c)
      emb_part[(size_t)(cgrp * 16 + c) * kNC + col] = acc[c];
  } else if (blk < 126) {
    __shared__ float ls[kB][kL];
    const int col = (blk - 112) * 256 + tid;
    for (int i = tid; i < kB * kL; i += 256) ls[i / kL][i % kL] = latent[i];
    __syncthreads();
    float acc[kB];
    const float bias = bc[col];
#pragma unroll
    for (int b = 0; b < kB; ++b) acc[b] = bias;
    for (int l = 0; l < kL; ++l) {
      const float w = Wc[(size_t)(kE + l) * kNC + col];
#pragma unroll
      for (int b = 0; b < kB; ++b) acc[b] = fmaf(ls[b][l], w, acc[b]);
    }
#pragma unroll
    for (int b = 0; b < kB; ++b) lat_part[(size_t)b * kNC + col] = acc[b];
  } else if (blk < 222) {
    const int tg = (blk - 126) * 256 + tid;
    for (int it = 0; it < 4; ++it) {
      const int item = tg + it * 24576;
      const int b = item / 3072;
      const int c6 = item % 3072;
      float a = bi[c6];
      for (int l = 0; l < kL; ++l)
        a = fmaf(latent[b * kL + l], Wi[(size_t)l * 3072 + c6], a);
      const int which = c6 >> 9;
      const int jl = c6 & 511;
      float* orow = out + (size_t)b * (kT + 1) * kOutRow;
      if (which == 0) {
        const float h = tanhf(a);
        orow[jl] = h;
        const unsigned int hh = f2bf(h);
        const unsigned int hl = f2bf(h - bf2f((unsigned short)hh));
        u32x2 v0 = {hh | (hl << 16), 0u};
        u32x2 v1 = {0u, 0xFFFFFFFFu};
        st_coh_x2(hdtag + (size_t)(b * kH + jl) * 2, v0);
        st_coh_x2(hdtag + (size_t)(kBH + b * kH + jl) * 2, v1);
      } else if (which == 1) {
        cd0[b * kH + jl] = tanhf(a);
      } else if (which == 2) {
        const float v = tanhf(a);
        orow[2 * kH + jl] = v;
        cb0[b * kH + jl] = v;
      } else if (which == 3) {
        orow[3 * kH + jl] = tanhf(a);
      } else if (which == 4) {
        orow[4 * kH + jl] = softplus_f(a);
      } else {
        orow[kH + jl] = sigmoid_f(a);
      }
    }
  } else {
    const int idx = (blk - 222) * 256 + tid;   // [0,16384)
    const int b = idx >> 9;
    const int t = idx & 511;
    dt[idx] = (t == 0) ? ts[b * kT] : ts[b * kT + t] - ts[b * kT + t - 1];
    if (blk == 222) st_coh_u32((unsigned int*)&flags[tid], 0u);
  }
}

// ---------------------------------------------------------------------------
// Sequential scan: 256 blocks = 8 batch-groups (4 batches) x 32 hidden-tiles
// (16 units). 8 waves x 64; wave w owns k-slice [w*64,w*64+64) for all 7
// gates (weights persistent, bf16 hi/lo). Per step, per wave:
//   1) poll 4 tile-FLAGS (16 B/round, cheap) until >= s-1
//   2) tagged fragment load direct from IF (2 KB unique/wave, ~1 round)
//   3) 42 MFMAs; partials -> parity-buffered pl
//   4) single __syncthreads; wave0: reduce + pointwise + publish h + flag.
// ---------------------------------------------------------------------------
__global__ __launch_bounds__(512, 2) void hawkes_seq(
    const int* __restrict__ marks, const float* __restrict__ Wc,
    float* __restrict__ out, const float* __restrict__ emb_part,
    const float* __restrict__ lat_part, const float* __restrict__ dt,
    const float* __restrict__ cd0, const float* __restrict__ cb0,
    unsigned int* __restrict__ hdtag, int* __restrict__ flags) {
  const int blk = blockIdx.x;
  const int bg = blk >> 5;                 // batch group 0..7
  const int jt = blk & 31;                 // hidden tile 0..31
  const int tid = threadIdx.x;
  const int wave = tid >> 6;               // k-slice 0..7
  const int lane = tid & 63;
  const int nl = lane & 15;                // A row / B col
  const int kg = lane >> 4;                // k-subgroup 0..3

  __shared__ float pl[2][8][7][16][4];     // parity-buffered partials, 28 KB

  // --- persistent weight fragments: 7 gates x 2 kt, hi/lo bf16 split ---
  s16x8 whi[7][2], wlo[7][2];
  {
    const float* Wh = Wc + (size_t)(kE + kL) * kNC;
    const int colbase = jt * 16 + nl;
#pragma unroll
    for (int g = 0; g < 7; ++g) {
#pragma unroll
      for (int kt = 0; kt < 2; ++kt) {
        s16x8 hi, lo;
#pragma unroll
        for (int e = 0; e < 8; ++e) {
          const float w =
              Wh[(size_t)(wave * 64 + kt * 32 + kg * 8 + e) * kNC +
                 g * kH + colbase];
          const unsigned short h = f2bf(w);
          hi[e] = (short)h;
          lo[e] = (short)f2bf(w - bf2f(h));
        }
        whi[g][kt] = hi;
        wlo[g][kt] = lo;
      }
    }
  }

  // --- pointwise lane state + rbias prefetch (wave 0 only) ---
  const int bl = lane >> 4;
  const int b_pw = bg * 4 + bl;
  const int j_pw = jt * 16 + nl;
  float c_d = 0.0f, c_bar = 0.0f, dtv = 0.0f;
  float rb[7];
#pragma unroll
  for (int m = 0; m < 7; ++m) rb[m] = 0.0f;
  if (wave == 0) {
    c_d = cd0[b_pw * kH + j_pw];
    c_bar = cb0[b_pw * kH + j_pw];
    const int mk = marks[b_pw * kT + 0];
    dtv = dt[b_pw * kT + 0];
#pragma unroll
    for (int m = 0; m < 7; ++m)
      rb[m] = emb_part[(size_t)mk * kNC + m * kH + j_pw] +
              lat_part[(size_t)b_pw * kNC + m * kH + j_pw];
  }

  const int arow = bg * 4 + (nl & 3);      // batch for A row (replicated x4)
  const int* fpoll = flags + bg * 32 + wave * 4 + (lane & 3);
  const size_t frag_elem = (size_t)(arow * kH + wave * 64 + kg * 8);

  for (int s = 1; s <= kT; ++s) {
    const unsigned int tg = (unsigned int)(s - 1);

    // ---- 1) cheap flag poll: 1 cacheline per wave per round ----
    if (s > 1) {
      const int target = s - 1;
      int v;
      do {
        v = ldflag(fpoll);
      } while (!__all(v >= target));
    }

    // ---- 2) tagged fragment load, direct from IF (retry ~1x) ----
    const char* ab = (const char*)hdtag +
                     ((size_t)((s - 1) & 1) * kBH + frag_elem) * 8;
    u32x4 d0, d1, d2, d3, d4, d5, d6, d7;
    for (;;) {
      asm volatile(
          "global_load_dwordx4 %0, %8, off sc0 sc1\n\t"
          "global_load_dwordx4 %1, %8, off offset:16 sc0 sc1\n\t"
          "global_load_dwordx4 %2, %8, off offset:32 sc0 sc1\n\t"
          "global_load_dwordx4 %3, %8, off offset:48 sc0 sc1\n\t"
          "global_load_dwordx4 %4, %8, off offset:256 sc0 sc1\n\t"
          "global_load_dwordx4 %5, %8, off offset:272 sc0 sc1\n\t"
          "global_load_dwordx4 %6, %8, off offset:288 sc0 sc1\n\t"
          "global_load_dwordx4 %7, %8, off offset:304 sc0 sc1\n\t"
          "s_waitcnt vmcnt(0)"
          : "=&v"(d0), "=&v"(d1), "=&v"(d2), "=&v"(d3), "=&v"(d4),
            "=&v"(d5), "=&v"(d6), "=&v"(d7)
          : "v"(ab) : "memory");
      const unsigned bad =
          (d0[1] ^ tg) | (d0[3] ^ tg) | (d1[1] ^ tg) | (d1[3] ^ tg) |
          (d2[1] ^ tg) | (d2[3] ^ tg) | (d3[1] ^ tg) | (d3[3] ^ tg) |
          (d4[1] ^ tg) | (d4[3] ^ tg) | (d5[1] ^ tg) | (d5[3] ^ tg) |
          (d6[1] ^ tg) | (d6[3] ^ tg) | (d7[1] ^ tg) | (d7[3] ^ tg);
      if (__all(bad == 0)) break;
    }
    s16x8 ah0, al0, ah1, al1;
    {
      u32x4 w0 = {d0[0], d0[2], d1[0], d1[2]};
      u32x4 w1 = {d2[0], d2[2], d3[0], d3[2]};
      unpack(w0, w1, ah0, al0);
      u32x4 w2 = {d4[0], d4[2], d5[0], d5[2]};
      u32x4 w3 = {d6[0], d6[2], d7[0], d7[2]};
      unpack(w2, w3, ah1, al1);
    }

    // ---- 3) partial GEMM: 7 gates x (2 kt x 3-term) ----
    const int p = s & 1;
    f32x4 acc[7];
#pragma unroll
    for (int g = 0; g < 7; ++g) {
      f32x4 a = {0.0f, 0.0f, 0.0f, 0.0f};
      a = mfma_bf16(al0, whi[g][0], a);
      a = mfma_bf16(ah0, wlo[g][0], a);
      a = mfma_bf16(ah0, whi[g][0], a);
      a = mfma_bf16(al1, whi[g][1], a);
      a = mfma_bf16(ah1, wlo[g][1], a);
      a = mfma_bf16(ah1, whi[g][1], a);
      acc[g] = a;
    }
    if (lane < 16) {
#pragma unroll
      for (int g = 0; g < 7; ++g)
        *(f32x4*)&pl[p][wave][g][nl][0] = acc[g];
    }
    __syncthreads();

    // ---- 4) reduce + pointwise + publish (wave 0 only) ----
    if (wave == 0) {
      float gv[7];
#pragma unroll
      for (int m = 0; m < 7; ++m) {
        float a = rb[m];
#pragma unroll
        for (int w = 0; w < 8; ++w) a += pl[p][w][m][nl][bl];
        gv[m] = a;
      }
      const float gi = fsigmoid(gv[0]);
      const float gf = fsigmoid(gv[1]);
      const float gz = ftanh(gv[2]);
      const float go = fsigmoid(gv[3]);
      const float gib = fsigmoid(gv[4]);
      const float gfb = fsigmoid(gv[5]);
      const float gd = fsoftplus(gv[6]);

      const float c = fmaf(gf, c_d, gi * gz);
      c_bar = fmaf(gfb, c_bar, gib * gz);
      c_d = c_bar + (c - c_bar) * fexp2(-gd * dtv * kLog2e);
      const float hd = go * ftanh(c_d);

      // tagged publish (fire-and-forget), then tile flag
      const unsigned int hh = f2bf(hd);
      const unsigned int hl = f2bf(hd - bf2f((unsigned short)hh));
      u32x2 pub = {hh | (hl << 16), (unsigned int)s};
      st_coh_x2(hdtag + (size_t)((s & 1) * kBH + b_pw * kH + j_pw) * 2, pub);
      if (lane == 0)
        st_coh_u32((unsigned int*)(flags + bg * 32 + jt), (unsigned int)s);

      float* orow = out + ((size_t)b_pw * (kT + 1) + s) * kOutRow;
      __builtin_nontemporal_store(hd, orow + j_pw);
      __builtin_nontemporal_store(go, orow + kH + j_pw);
      __builtin_nontemporal_store(c_bar, orow + 2 * kH + j_pw);
      __builtin_nontemporal_store(c, orow + 3 * kH + j_pw);
      __builtin_nontemporal_store(gd, orow + 4 * kH + j_pw);

      // prefetch next step's rbias/dt (off critical path)
      if (s < kT) {
        const int mk = marks[b_pw * kT + s];
        dtv = dt[b_pw * kT + s];
#pragma unroll
        for (int m = 0; m < 7; ++m)
          rb[m] = emb_part[(size_t)mk * kNC + m * kH + j_pw] +
                  lat_part[(size_t)b_pw * kNC + m * kH + j_pw];
      }
    }
  }
}

}  // namespace

extern "C" void kernel_launch(void* const* d_in, const int* in_sizes, int n_in,
                              void* d_out, int out_size, void* d_ws,
                              size_t ws_size, hipStream_t stream) {
  const int* marks = (const int*)d_in[0];
  const float* ts = (const float*)d_in[1];
  const float* latent = (const float*)d_in[2];
  const float* emb = (const float*)d_in[3];
  const float* Wc = (const float*)d_in[4];
  const float* bc = (const float*)d_in[5];
  const float* Wi = (const float*)d_in[6];
  const float* bi = (const float*)d_in[7];
  float* out = (float*)d_out;

  char* ws = (char*)d_ws;
  float* emb_part = (float*)(ws + 0);                 // 1,835,008 B
  float* lat_part = (float*)(ws + 1835008);           //   458,752 B
  float* dt       = (float*)(ws + 2293760);           //    65,536 B
  float* cd0      = (float*)(ws + 2359296);           //    65,536 B
  float* cb0      = (float*)(ws + 2424832);           //    65,536 B
  unsigned int* hdtag = (unsigned int*)(ws + 2490368); //  262,144 B
  int* flags      = (int*)(ws + 2752512);             //     1,024 B

  hawkes_setup<<<286, 256, 0, stream>>>(ts, latent, emb, Wc, bc, Wi, bi, out,
                                        emb_part, lat_part, dt, cd0, cb0,
                                        hdtag, flags);
  hawkes_seq<<<256, 512, 0, stream>>>(marks, Wc, out, emb_part, lat_part, dt,
                                      cd0, cb0, hdtag, flags);
}

// Round 9
// 1774.465 us; speedup vs baseline: 1.4656x; 1.4656x over previous
//
#include <hip/hip_runtime.h>
#include <hip/hip_bf16.h>

namespace {

constexpr int kB = 32;
constexpr int kT = 512;
constexpr int kH = 512;
constexpr int kE = 256;
constexpr int kL = 64;
constexpr int kNC = 7 * kH;       // 3584 gate columns
constexpr int kOutRow = 5 * kH;   // 2560
constexpr int kBH = kB * kH;      // 16384 packets per parity slot

typedef float f32x4 __attribute__((ext_vector_type(4)));
typedef short s16x8 __attribute__((ext_vector_type(8)));
typedef __bf16 bf16x8 __attribute__((ext_vector_type(8)));
typedef unsigned int u32x4 __attribute__((ext_vector_type(4)));
typedef unsigned int u32x2 __attribute__((ext_vector_type(2)));

__device__ __forceinline__ unsigned short f2bf(float f) {
  __hip_bfloat16 h = __float2bfloat16(f);
  return __builtin_bit_cast(unsigned short, h);
}

__device__ __forceinline__ float bf2f(unsigned short u) {
  return __builtin_bit_cast(float, (unsigned int)u << 16);
}

// libm versions (setup only)
__device__ __forceinline__ float sigmoid_f(float x) {
  return 1.0f / (1.0f + expf(-x));
}
__device__ __forceinline__ float softplus_f(float x) {
  return fmaxf(x, 0.0f) + log1pf(expf(-fabsf(x)));
}

// fast versions (hot kernel)
constexpr float kLog2e = 1.4426950408889634f;
constexpr float kLn2 = 0.6931471805599453f;
__device__ __forceinline__ float fexp2(float x) {
  return __builtin_amdgcn_exp2f(x);
}
__device__ __forceinline__ float frcp(float x) {
  return __builtin_amdgcn_rcpf(x);
}
__device__ __forceinline__ float fsigmoid(float x) {
  return frcp(1.0f + fexp2(-x * kLog2e));
}
__device__ __forceinline__ float ftanh(float x) {
  return 1.0f - 2.0f * frcp(1.0f + fexp2((2.0f * kLog2e) * x));
}
__device__ __forceinline__ float fsoftplus(float x) {
  return fmaxf(x, 0.0f) +
         kLn2 * __builtin_amdgcn_logf(1.0f + fexp2(-fabsf(x) * kLog2e));
}

__device__ __forceinline__ f32x4 mfma_bf16(s16x8 a, s16x8 b, f32x4 c) {
  return __builtin_amdgcn_mfma_f32_16x16x32_bf16(
      __builtin_bit_cast(bf16x8, a), __builtin_bit_cast(bf16x8, b), c, 0, 0, 0);
}

// Device-coherent ops (PROVEN protocol: sc0 sc1 fused tagged packets).
__device__ __forceinline__ void st_coh_x2(unsigned int* p, u32x2 v) {
  asm volatile("global_store_dwordx2 %0, %1, off sc0 sc1" :: "v"(p), "v"(v)
               : "memory");
}

// lgkm-only barrier: orders LDS without draining outstanding VMEM
// (publish / out-stores / rbias prefetch stay in flight across steps).
__device__ __forceinline__ void barrier_lds() {
  __builtin_amdgcn_sched_barrier(0);
  asm volatile("s_waitcnt lgkmcnt(0)\n\ts_barrier" ::: "memory");
  __builtin_amdgcn_sched_barrier(0);
}

__device__ __forceinline__ void unpack(const u32x4& x0, const u32x4& x1,
                                       s16x8& hi, s16x8& lo) {
#pragma unroll
  for (int e = 0; e < 4; ++e) {
    hi[e] = (short)(x0[e] & 0xffffu);
    hi[e + 4] = (short)(x1[e] & 0xffffu);
    lo[e] = (short)(x0[e] >> 16);
    lo[e + 4] = (short)(x1[e] >> 16);
  }
}

// ---------------------------------------------------------------------------
// Setup: emb_part [128][3584], lat_part(+bias) [32][3584], dt [32][512],
// init states -> out row 0, hdtag parity0 = {packed h0, tag 0}, parity1
// poisoned. (Re-seeded every launch: replay-safe.)
// ---------------------------------------------------------------------------
__global__ void hawkes_setup(const float* __restrict__ ts,
                             const float* __restrict__ latent,
                             const float* __restrict__ emb,
                             const float* __restrict__ Wc,
                             const float* __restrict__ bc,
                             const float* __restrict__ Wi,
                             const float* __restrict__ bi,
                             float* __restrict__ out,
                             float* __restrict__ emb_part,
                             float* __restrict__ lat_part,
                             float* __restrict__ dt,
                             float* __restrict__ cd0,
                             float* __restrict__ cb0,
                             unsigned int* __restrict__ hdtag) {
  const int blk = blockIdx.x;
  const int tid = threadIdx.x;
  if (blk < 112) {
    __shared__ float es[16][kE];
    const int cgrp = blk / 14;
    const int col = (blk % 14) * 256 + tid;
    for (int i = tid; i < 16 * kE; i += 256)
      es[i / kE][i % kE] = emb[(cgrp * 16 + i / kE) * kE + (i % kE)];
    __syncthreads();
    float acc[16];
#pragma unroll
    for (int c = 0; c < 16; ++c) acc[c] = 0.0f;
    for (int e = 0; e < kE; ++e) {
      const float w = Wc[(size_t)e * kNC + col];
#pragma unroll
      for (int c = 0; c < 16; ++c) acc[c] = fmaf(es[c][e], w, acc[c]);
    }
#pragma unroll
    for (int c = 0; c < 16; ++c)
      emb_part[(size_t)(cgrp * 16 + c) * kNC + col] = acc[c];
  } else if (blk < 126) {
    __shared__ float ls[kB][kL];
    const int col = (blk - 112) * 256 + tid;
    for (int i = tid; i < kB * kL; i += 256) ls[i / kL][i % kL] = latent[i];
    __syncthreads();
    float acc[kB];
    const float bias = bc[col];
#pragma unroll
    for (int b = 0; b < kB; ++b) acc[b] = bias;
    for (int l = 0; l < kL; ++l) {
      const float w = Wc[(size_t)(kE + l) * kNC + col];
#pragma unroll
      for (int b = 0; b < kB; ++b) acc[b] = fmaf(ls[b][l], w, acc[b]);
    }
#pragma unroll
    for (int b = 0; b < kB; ++b) lat_part[(size_t)b * kNC + col] = acc[b];
  } else if (blk < 222) {
    const int tg = (blk - 126) * 256 + tid;
    for (int it = 0; it < 4; ++it) {
      const int item = tg + it * 24576;
      const int b = item / 3072;
      const int c6 = item % 3072;
      float a = bi[c6];
      for (int l = 0; l < kL; ++l)
        a = fmaf(latent[b * kL + l], Wi[(size_t)l * 3072 + c6], a);
      const int which = c6 >> 9;
      const int jl = c6 & 511;
      float* orow = out + (size_t)b * (kT + 1) * kOutRow;
      if (which == 0) {
        const float h = tanhf(a);
        orow[jl] = h;
        const unsigned int hh = f2bf(h);
        const unsigned int hl = f2bf(h - bf2f((unsigned short)hh));
        u32x2 v0 = {hh | (hl << 16), 0u};
        u32x2 v1 = {0u, 0xFFFFFFFFu};
        st_coh_x2(hdtag + (size_t)(b * kH + jl) * 2, v0);
        st_coh_x2(hdtag + (size_t)(kBH + b * kH + jl) * 2, v1);
      } else if (which == 1) {
        cd0[b * kH + jl] = tanhf(a);
      } else if (which == 2) {
        const float v = tanhf(a);
        orow[2 * kH + jl] = v;
        cb0[b * kH + jl] = v;
      } else if (which == 3) {
        orow[3 * kH + jl] = tanhf(a);
      } else if (which == 4) {
        orow[4 * kH + jl] = softplus_f(a);
      } else {
        orow[kH + jl] = sigmoid_f(a);
      }
    }
  } else {
    const int idx = (blk - 222) * 256 + tid;   // [0,16384)
    const int b = idx >> 9;
    const int t = idx & 511;
    dt[idx] = (t == 0) ? ts[b * kT] : ts[b * kT + t] - ts[b * kT + t - 1];
  }
}

// ---------------------------------------------------------------------------
// Sequential scan: 256 blocks = 8 batch-groups (4 batches) x 32 hidden-tiles
// (16 units). 8 waves x 64; wave w owns k-slice [w*64,(w+1)*64) for all 7
// gates (weights persistent, bf16 hi/lo, 3-term MFMA). PROVEN R3 exchange:
// 8 B {packed hi|lo, tag} sc0sc1 packets, parity double-buffer, exact tag.
// New structure per step:
//   1) wave-local tagged poll of OWN k-slice (4 source tiles) -> own LDS
//      slice; lgkmcnt only, NO block barrier (stagger absorbs jitter).
//   2) 42 MFMAs; partials -> pl; B2 (lgkm-only barrier).
//   3) waves 0-6: reduce + activate gate w -> act; rbias prefetch. B3.
//   4) wave 7: state update + sc0sc1 publish + out stores.
// ---------------------------------------------------------------------------
__global__ __launch_bounds__(512) void hawkes_seq(
    const int* __restrict__ marks, const float* __restrict__ Wc,
    float* __restrict__ out, const float* __restrict__ emb_part,
    const float* __restrict__ lat_part, const float* __restrict__ dt,
    const float* __restrict__ cd0, const float* __restrict__ cb0,
    unsigned int* __restrict__ hdtag) {
  const int blk = blockIdx.x;
  const int bg = blk >> 5;                 // batch group 0..7
  const int jt = blk & 31;                 // hidden tile 0..31
  const int tid = threadIdx.x;
  const int wave = tid >> 6;               // 0..7 = k-slice
  const int lane = tid & 63;
  const int nl = lane & 15;                // A row / B col
  const int kg = lane >> 4;                // k-subgroup 0..3

  __shared__ __align__(16) unsigned int lds_a[4][516];  // packed hi|lo
  __shared__ __align__(16) float pl[8][7][16][4];
  __shared__ __align__(16) float act[7][16][4];

  // ---- persistent weights: 7 gates x 2 kt, bf16 hi/lo split ----
  s16x8 whi[7][2], wlo[7][2];
  {
    const float* Wh = Wc + (size_t)(kE + kL) * kNC;
    const int colbase = jt * 16 + nl;
#pragma unroll
    for (int gg = 0; gg < 7; ++gg) {
#pragma unroll
      for (int kt = 0; kt < 2; ++kt) {
        s16x8 hi, lo;
#pragma unroll
        for (int e = 0; e < 8; ++e) {
          const float w =
              Wh[(size_t)(wave * 64 + kt * 32 + kg * 8 + e) * kNC +
                 gg * kH + colbase];
          const unsigned short h = f2bf(w);
          hi[e] = (short)h;
          lo[e] = (short)f2bf(w - bf2f(h));
        }
        whi[gg][kt] = hi;
        wlo[gg][kt] = lo;
      }
    }
  }

  // ---- per-lane tail identities ----
  const int bl = lane >> 4;                // local batch 0..3
  const int b_pw = bg * 4 + bl;
  const int j_pw = jt * 16 + nl;

  float c_d = 0.0f, c_bar = 0.0f, dtv = 0.0f, rb = 0.0f;
  if (wave == 7) {
    c_d = cd0[b_pw * kH + j_pw];
    c_bar = cb0[b_pw * kH + j_pw];
    dtv = dt[b_pw * kT + 0];
  } else {
    const int mk = marks[b_pw * kT + 0];
    rb = emb_part[(size_t)mk * kNC + wave * kH + j_pw] +
         lat_part[(size_t)b_pw * kNC + wave * kH + j_pw];
  }

  // ---- wave-local poll assignment: wave w loads its own k-slice ----
  const int b_ld = lane >> 4;              // 0..3
  const int k_ld = wave * 64 + (lane & 15) * 4;
  unsigned int* ld_base = hdtag + (size_t)((bg * 4 + b_ld) * kH + k_ld) * 2;

  for (int s = 1; s <= kT; ++s) {
    // ---- 1) wave-local tagged poll (proven sc0sc1 fused packets) ----
    const unsigned int tg = (unsigned int)(s - 1);
    unsigned int* lp = ld_base + (size_t)((s - 1) & 1) * (kBH * 2);
    u32x4 d0, d1;
    int guard = 0;
    for (;;) {
      asm volatile(
          "global_load_dwordx4 %0, %2, off sc0 sc1\n\t"
          "global_load_dwordx4 %1, %2, off offset:16 sc0 sc1\n\t"
          "s_waitcnt vmcnt(0)"
          : "=v"(d0), "=v"(d1) : "v"(lp) : "memory");
      if (d0[1] == tg && d0[3] == tg && d1[1] == tg && d1[3] == tg) break;
      if (++guard > (1 << 15)) break;      // safety valve: fail, don't hang
    }
    {
      u32x4 w = {d0[0], d0[2], d1[0], d1[2]};
      *(u32x4*)&lds_a[b_ld][k_ld] = w;
    }
    // same-wave LDS visibility only: no block barrier needed
    __builtin_amdgcn_sched_barrier(0);
    asm volatile("s_waitcnt lgkmcnt(0)" ::: "memory");
    __builtin_amdgcn_sched_barrier(0);

    // ---- 2) partial GEMM: 7 gates x 2 kt x 3-term ----
    const unsigned int* ap = &lds_a[nl & 3][wave * 64 + kg * 8];
    u32x4 x0 = *(const u32x4*)(ap);
    u32x4 x1 = *(const u32x4*)(ap + 4);
    u32x4 x2 = *(const u32x4*)(ap + 32);
    u32x4 x3 = *(const u32x4*)(ap + 36);
    s16x8 ah0, al0, ah1, al1;
    unpack(x0, x1, ah0, al0);
    unpack(x2, x3, ah1, al1);

    f32x4 acc[7];
#pragma unroll
    for (int gg = 0; gg < 7; ++gg) {
      f32x4 a = {0.0f, 0.0f, 0.0f, 0.0f};
      a = mfma_bf16(al0, whi[gg][0], a);
      a = mfma_bf16(ah0, wlo[gg][0], a);
      a = mfma_bf16(ah0, whi[gg][0], a);
      a = mfma_bf16(al1, whi[gg][1], a);
      a = mfma_bf16(ah1, wlo[gg][1], a);
      a = mfma_bf16(ah1, whi[gg][1], a);
      acc[gg] = a;
    }
    if (lane < 16) {
#pragma unroll
      for (int gg = 0; gg < 7; ++gg)
        *(f32x4*)&pl[wave][gg][lane][0] = acc[gg];
    }
    barrier_lds();                          // B2

    // ---- 3) gate reduce + activation (waves 0..6, gate = wave) ----
    if (wave < 7) {
      float a = rb;
#pragma unroll
      for (int w = 0; w < 8; ++w) a += pl[w][wave][nl][bl];
      float v;
      if (wave == 2) v = ftanh(a);
      else if (wave == 6) v = fsoftplus(a);
      else v = fsigmoid(a);
      act[wave][nl][bl] = v;
      if (s < kT) {                         // prefetch next rbias
        const int mk = marks[b_pw * kT + s];
        rb = emb_part[(size_t)mk * kNC + wave * kH + j_pw] +
             lat_part[(size_t)b_pw * kNC + wave * kH + j_pw];
      }
    }
    barrier_lds();                          // B3

    // ---- 4) state update + publish (wave 7) ----
    if (wave == 7) {
      const float gi = act[0][nl][bl];
      const float gf = act[1][nl][bl];
      const float gz = act[2][nl][bl];
      const float go = act[3][nl][bl];
      const float gib = act[4][nl][bl];
      const float gfb = act[5][nl][bl];
      const float gd = act[6][nl][bl];

      const float c = fmaf(gf, c_d, gi * gz);
      c_bar = fmaf(gfb, c_bar, gib * gz);
      c_d = c_bar + (c - c_bar) * fexp2(-gd * dtv * kLog2e);
      const float hd = go * ftanh(c_d);

      // tagged publish (fire-and-forget, proven sc0sc1 8 B packet)
      const unsigned int hh = f2bf(hd);
      const unsigned int hl = f2bf(hd - bf2f((unsigned short)hh));
      u32x2 pub = {hh | (hl << 16), (unsigned int)s};
      st_coh_x2(hdtag + (size_t)((s & 1) * kBH + b_pw * kH + j_pw) * 2, pub);

      float* orow = out + ((size_t)b_pw * (kT + 1) + s) * kOutRow;
      __builtin_nontemporal_store(hd, orow + j_pw);
      __builtin_nontemporal_store(go, orow + kH + j_pw);
      __builtin_nontemporal_store(c_bar, orow + 2 * kH + j_pw);
      __builtin_nontemporal_store(c, orow + 3 * kH + j_pw);
      __builtin_nontemporal_store(gd, orow + 4 * kH + j_pw);

      if (s < kT) dtv = dt[b_pw * kT + s];
    }
  }
}

}  // namespace

extern "C" void kernel_launch(void* const* d_in, const int* in_sizes, int n_in,
                              void* d_out, int out_size, void* d_ws,
                              size_t ws_size, hipStream_t stream) {
  const int* marks = (const int*)d_in[0];
  const float* ts = (const float*)d_in[1];
  const float* latent = (const float*)d_in[2];
  const float* emb = (const float*)d_in[3];
  const float* Wc = (const float*)d_in[4];
  const float* bc = (const float*)d_in[5];
  const float* Wi = (const float*)d_in[6];
  const float* bi = (const float*)d_in[7];
  float* out = (float*)d_out;

  char* ws = (char*)d_ws;
  float* emb_part = (float*)(ws + 0);                  // 1,835,008 B
  float* lat_part = (float*)(ws + 1835008);            //   458,752 B
  float* dt       = (float*)(ws + 2293760);            //    65,536 B
  float* cd0      = (float*)(ws + 2359296);            //    65,536 B
  float* cb0      = (float*)(ws + 2424832);            //    65,536 B
  unsigned int* hdtag = (unsigned int*)(ws + 2490368); //   262,144 B

  hawkes_setup<<<286, 256, 0, stream>>>(ts, latent, emb, Wc, bc, Wi, bi, out,
                                        emb_part, lat_part, dt, cd0, cb0,
                                        hdtag);
  hawkes_seq<<<256, 512, 0, stream>>>(marks, Wc, out, emb_part, lat_part, dt,
                                      cd0, cb0, hdtag);
}

// Round 10
// 1597.222 us; speedup vs baseline: 1.6282x; 1.1110x over previous
//
#include <hip/hip_runtime.h>
#include <hip/hip_bf16.h>

namespace {

constexpr int kB = 32;
constexpr int kT = 512;
constexpr int kH = 512;
constexpr int kE = 256;
constexpr int kL = 64;
constexpr int kNC = 7 * kH;       // 3584 gate columns
constexpr int kOutRow = 5 * kH;   // 2560
constexpr int kBH = kB * kH;      // 16384 packets per parity slot

typedef float f32x4 __attribute__((ext_vector_type(4)));
typedef short s16x8 __attribute__((ext_vector_type(8)));
typedef __bf16 bf16x8 __attribute__((ext_vector_type(8)));
typedef unsigned int u32x4 __attribute__((ext_vector_type(4)));
typedef unsigned int u32x2 __attribute__((ext_vector_type(2)));

__device__ __forceinline__ unsigned short f2bf(float f) {
  __hip_bfloat16 h = __float2bfloat16(f);
  return __builtin_bit_cast(unsigned short, h);
}

__device__ __forceinline__ float bf2f(unsigned short u) {
  return __builtin_bit_cast(float, (unsigned int)u << 16);
}

// libm versions (setup only)
__device__ __forceinline__ float sigmoid_f(float x) {
  return 1.0f / (1.0f + expf(-x));
}
__device__ __forceinline__ float softplus_f(float x) {
  return fmaxf(x, 0.0f) + log1pf(expf(-fabsf(x)));
}

// fast versions (hot kernel): v_exp_f32 / v_log_f32 / v_rcp_f32
constexpr float kLog2e = 1.4426950408889634f;
constexpr float kLn2 = 0.6931471805599453f;
__device__ __forceinline__ float fexp2(float x) {
  return __builtin_amdgcn_exp2f(x);
}
__device__ __forceinline__ float frcp(float x) {
  return __builtin_amdgcn_rcpf(x);
}
__device__ __forceinline__ float fsigmoid(float x) {
  return frcp(1.0f + fexp2(-x * kLog2e));
}
__device__ __forceinline__ float ftanh(float x) {
  return 1.0f - 2.0f * frcp(1.0f + fexp2((2.0f * kLog2e) * x));
}
__device__ __forceinline__ float fsoftplus(float x) {
  return fmaxf(x, 0.0f) +
         kLn2 * __builtin_amdgcn_logf(1.0f + fexp2(-fabsf(x) * kLog2e));
}

__device__ __forceinline__ f32x4 mfma_bf16(s16x8 a, s16x8 b, f32x4 c) {
  return __builtin_amdgcn_mfma_f32_16x16x32_bf16(
      __builtin_bit_cast(bf16x8, a), __builtin_bit_cast(bf16x8, b), c, 0, 0, 0);
}

__device__ __forceinline__ void st_coh_x2(unsigned int* p, u32x2 v) {
  asm volatile("global_store_dwordx2 %0, %1, off sc0 sc1" :: "v"(p), "v"(v)
               : "memory");
}

__device__ __forceinline__ void unpack(const u32x4& x0, const u32x4& x1,
                                       s16x8& hi, s16x8& lo) {
#pragma unroll
  for (int e = 0; e < 4; ++e) {
    hi[e] = (short)(x0[e] & 0xffffu);
    hi[e + 4] = (short)(x1[e] & 0xffffu);
    lo[e] = (short)(x0[e] >> 16);
    lo[e + 4] = (short)(x1[e] >> 16);
  }
}

// ---------------------------------------------------------------------------
// Setup: emb_part [128][3584], lat_part(+bias) [32][3584], dt [32][512],
// init states -> out row 0, hdtag parity0 = {h0, tag 0}, parity1 poisoned.
// ---------------------------------------------------------------------------
__global__ void hawkes_setup(const float* __restrict__ ts,
                             const float* __restrict__ latent,
                             const float* __restrict__ emb,
                             const float* __restrict__ Wc,
                             const float* __restrict__ bc,
                             const float* __restrict__ Wi,
                             const float* __restrict__ bi,
                             float* __restrict__ out,
                             float* __restrict__ emb_part,
                             float* __restrict__ lat_part,
                             float* __restrict__ dt,
                             float* __restrict__ cd0,
                             float* __restrict__ cb0,
                             unsigned int* __restrict__ hdtag) {
  const int blk = blockIdx.x;
  const int tid = threadIdx.x;
  if (blk < 112) {
    __shared__ float es[16][kE];
    const int cgrp = blk / 14;
    const int col = (blk % 14) * 256 + tid;
    for (int i = tid; i < 16 * kE; i += 256)
      es[i / kE][i % kE] = emb[(cgrp * 16 + i / kE) * kE + (i % kE)];
    __syncthreads();
    float acc[16];
#pragma unroll
    for (int c = 0; c < 16; ++c) acc[c] = 0.0f;
    for (int e = 0; e < kE; ++e) {
      const float w = Wc[(size_t)e * kNC + col];
#pragma unroll
      for (int c = 0; c < 16; ++c) acc[c] = fmaf(es[c][e], w, acc[c]);
    }
#pragma unroll
    for (int c = 0; c < 16; ++c)
      emb_part[(size_t)(cgrp * 16 + c) * kNC + col] = acc[c];
  } else if (blk < 126) {
    __shared__ float ls[kB][kL];
    const int col = (blk - 112) * 256 + tid;
    for (int i = tid; i < kB * kL; i += 256) ls[i / kL][i % kL] = latent[i];
    __syncthreads();
    float acc[kB];
    const float bias = bc[col];
#pragma unroll
    for (int b = 0; b < kB; ++b) acc[b] = bias;
    for (int l = 0; l < kL; ++l) {
      const float w = Wc[(size_t)(kE + l) * kNC + col];
#pragma unroll
      for (int b = 0; b < kB; ++b) acc[b] = fmaf(ls[b][l], w, acc[b]);
    }
#pragma unroll
    for (int b = 0; b < kB; ++b) lat_part[(size_t)b * kNC + col] = acc[b];
  } else if (blk < 222) {
    const int tg = (blk - 126) * 256 + tid;
    for (int it = 0; it < 4; ++it) {
      const int item = tg + it * 24576;
      const int b = item / 3072;
      const int c6 = item % 3072;
      float a = bi[c6];
      for (int l = 0; l < kL; ++l)
        a = fmaf(latent[b * kL + l], Wi[(size_t)l * 3072 + c6], a);
      const int which = c6 >> 9;
      const int jl = c6 & 511;
      float* orow = out + (size_t)b * (kT + 1) * kOutRow;
      if (which == 0) {
        const float h = tanhf(a);
        orow[jl] = h;
        const unsigned int hh = f2bf(h);
        const unsigned int hl = f2bf(h - bf2f((unsigned short)hh));
        u32x2 v0 = {hh | (hl << 16), 0u};
        u32x2 v1 = {0u, 0xFFFFFFFFu};
        st_coh_x2(hdtag + (size_t)(b * kH + jl) * 2, v0);
        st_coh_x2(hdtag + (size_t)(kBH + b * kH + jl) * 2, v1);
      } else if (which == 1) {
        cd0[b * kH + jl] = tanhf(a);
      } else if (which == 2) {
        const float v = tanhf(a);
        orow[2 * kH + jl] = v;
        cb0[b * kH + jl] = v;
      } else if (which == 3) {
        orow[3 * kH + jl] = tanhf(a);
      } else if (which == 4) {
        orow[4 * kH + jl] = softplus_f(a);
      } else {
        orow[kH + jl] = sigmoid_f(a);
      }
    }
  } else {
    const int idx = (blk - 222) * 256 + tid;   // [0,16384)
    const int b = idx >> 9;
    const int t = idx & 511;
    dt[idx] = (t == 0) ? ts[b * kT] : ts[b * kT + t] - ts[b * kT + t - 1];
  }
}

// ---------------------------------------------------------------------------
// Sequential scan (R3-proven structure): 256 blocks = 8 batch-groups (4
// batches) x 32 hidden-tiles (16 units). 8 waves x 64; wave w owns k-slice
// [w*64,w*64+64) for all 7 gates (weights persistent, bf16 hi/lo). Per step:
//   1) 512 threads cooperatively load 2048 tagged h_d packets from IF
//      (retry until tag==s-1; the poll IS the data load), stage to LDS.
//      NEW: s_sleep(2) backoff on each failed round -- cuts spin-load
//      traffic at the IF coherence point ~5-10x (T1 congestion test).
//   2) sync; waves ds_read fragments, 42 MFMAs, partials -> LDS.
//   3) sync; wave0 reduces, pointwise, publishes {h_d, tag=s} fire-and-forget.
// ---------------------------------------------------------------------------
__global__ __launch_bounds__(512, 2) void hawkes_seq(
    const int* __restrict__ marks, const float* __restrict__ Wc,
    float* __restrict__ out, const float* __restrict__ emb_part,
    const float* __restrict__ lat_part, const float* __restrict__ dt,
    const float* __restrict__ cd0, const float* __restrict__ cb0,
    unsigned int* __restrict__ hdtag) {
  const int blk = blockIdx.x;
  const int bg = blk >> 5;                 // batch group 0..7
  const int jt = blk & 31;                 // hidden tile 0..31
  const int tid = threadIdx.x;
  const int wave = tid >> 6;               // k-slice 0..7
  const int lane = tid & 63;
  const int nl = lane & 15;                // fragment column / A row
  const int kg = lane >> 4;                // k-subgroup 0..3

  __shared__ __align__(16) unsigned int lds_a[4][516];  // packed hi|lo, pad 4
  __shared__ float pl[8][7][16][4];                     // [kwave][gate][j][b]

  // --- persistent weight fragments: 7 gates x 2 kt, hi/lo bf16 split ---
  s16x8 whi[7][2], wlo[7][2];
  {
    const float* Wh = Wc + (size_t)(kE + kL) * kNC;
    const int colbase = jt * 16 + nl;
#pragma unroll
    for (int g = 0; g < 7; ++g) {
#pragma unroll
      for (int kt = 0; kt < 2; ++kt) {
        s16x8 hi, lo;
#pragma unroll
        for (int e = 0; e < 8; ++e) {
          const float w =
              Wh[(size_t)(wave * 64 + kt * 32 + kg * 8 + e) * kNC +
                 g * kH + colbase];
          const unsigned short h = f2bf(w);
          hi[e] = (short)h;
          lo[e] = (short)f2bf(w - bf2f(h));
        }
        whi[g][kt] = hi;
        wlo[g][kt] = lo;
      }
    }
  }

  // --- cooperative tagged-load assignment: 4 packets per thread ---
  const int t4 = tid * 4;                  // 0..2044
  const int b_ld = t4 >> 9;                // local batch 0..3
  const int k_ld = t4 & 511;
  unsigned int* ld_base =
      hdtag + (size_t)((bg * 4 + b_ld) * kH + k_ld) * 2;

  // --- pointwise lane state + rbias prefetch (wave 0 only) ---
  const int bl = lane >> 4;                // b_local for pointwise
  const int b_pw = bg * 4 + bl;
  const int j_pw = jt * 16 + nl;
  float c_d = 0.0f, c_bar = 0.0f, dtv = 0.0f;
  float rb[7];
#pragma unroll
  for (int m = 0; m < 7; ++m) rb[m] = 0.0f;
  if (wave == 0) {
    c_d = cd0[b_pw * kH + j_pw];
    c_bar = cb0[b_pw * kH + j_pw];
    const int mk = marks[b_pw * kT + 0];
    dtv = dt[b_pw * kT + 0];
#pragma unroll
    for (int m = 0; m < 7; ++m)
      rb[m] = emb_part[(size_t)mk * kNC + m * kH + j_pw] +
              lat_part[(size_t)b_pw * kNC + m * kH + j_pw];
  }

  for (int s = 1; s <= kT; ++s) {
    // ---- 1) tagged cooperative load (poll == data load, sleep backoff) ----
    const unsigned int tg = (unsigned int)(s - 1);
    unsigned int* lp = ld_base + (size_t)((s - 1) & 1) * (kBH * 2);
    u32x4 d0, d1;
    for (;;) {
      asm volatile(
          "global_load_dwordx4 %0, %2, off sc0 sc1\n\t"
          "global_load_dwordx4 %1, %2, off offset:16 sc0 sc1\n\t"
          "s_waitcnt vmcnt(0)"
          : "=v"(d0), "=v"(d1) : "v"(lp) : "memory");
      if (d0[1] == tg && d0[3] == tg && d1[1] == tg && d1[3] == tg) break;
      asm volatile("s_sleep 2" ::: "memory");   // ~128 cy off the fabric
    }
    {
      u32x4 w = {d0[0], d0[2], d1[0], d1[2]};
      *(u32x4*)&lds_a[b_ld][k_ld] = w;
    }
    __syncthreads();

    // ---- 2) fragment reads + partial GEMM: 7 gates x (2 kt x 3-term) ----
    const unsigned int* ap = &lds_a[nl & 3][wave * 64 + kg * 8];
    u32x4 x0 = *(const u32x4*)(ap);
    u32x4 x1 = *(const u32x4*)(ap + 4);
    u32x4 x2 = *(const u32x4*)(ap + 32);
    u32x4 x3 = *(const u32x4*)(ap + 36);
    s16x8 ah0, al0, ah1, al1;
    unpack(x0, x1, ah0, al0);
    unpack(x2, x3, ah1, al1);

    f32x4 acc[7];
#pragma unroll
    for (int g = 0; g < 7; ++g) {
      f32x4 a = {0.0f, 0.0f, 0.0f, 0.0f};
      a = mfma_bf16(ah0, whi[g][0], a);
      a = mfma_bf16(ah0, wlo[g][0], a);
      a = mfma_bf16(al0, whi[g][0], a);
      a = mfma_bf16(ah1, whi[g][1], a);
      a = mfma_bf16(ah1, wlo[g][1], a);
      a = mfma_bf16(al1, whi[g][1], a);
      acc[g] = a;
    }
    if (lane < 16) {
#pragma unroll
      for (int g = 0; g < 7; ++g)
        *(f32x4*)&pl[wave][g][nl][0] = acc[g];
    }
    __syncthreads();

    // ---- 3) reduce + pointwise + publish (wave 0: 4 b x 16 j) ----
    if (wave == 0) {
      float g[7];
#pragma unroll
      for (int m = 0; m < 7; ++m) {
        float a = rb[m];
#pragma unroll
        for (int w = 0; w < 8; ++w) a += pl[w][m][nl][bl];
        g[m] = a;
      }
      const float gi = fsigmoid(g[0]);
      const float gf = fsigmoid(g[1]);
      const float gz = ftanh(g[2]);
      const float go = fsigmoid(g[3]);
      const float gib = fsigmoid(g[4]);
      const float gfb = fsigmoid(g[5]);
      const float gd = fsoftplus(g[6]);

      const float c = fmaf(gf, c_d, gi * gz);
      c_bar = fmaf(gfb, c_bar, gib * gz);
      c_d = c_bar + (c - c_bar) * fexp2(-gd * dtv * kLog2e);
      const float hd = go * ftanh(c_d);

      // fire-and-forget tagged publish (atomic 8B store, no ack wait)
      const unsigned int hh = f2bf(hd);
      const unsigned int hl = f2bf(hd - bf2f((unsigned short)hh));
      u32x2 pub = {hh | (hl << 16), (unsigned int)s};
      st_coh_x2(hdtag + (size_t)((s & 1) * kBH + b_pw * kH + j_pw) * 2, pub);

      float* orow = out + ((size_t)b_pw * (kT + 1) + s) * kOutRow;
      __builtin_nontemporal_store(hd, orow + j_pw);
      __builtin_nontemporal_store(go, orow + kH + j_pw);
      __builtin_nontemporal_store(c_bar, orow + 2 * kH + j_pw);
      __builtin_nontemporal_store(c, orow + 3 * kH + j_pw);
      __builtin_nontemporal_store(gd, orow + 4 * kH + j_pw);

      // prefetch next step's rbias/dt (off critical path)
      if (s < kT) {
        const int mk = marks[b_pw * kT + s];
        dtv = dt[b_pw * kT + s];
#pragma unroll
        for (int m = 0; m < 7; ++m)
          rb[m] = emb_part[(size_t)mk * kNC + m * kH + j_pw] +
                  lat_part[(size_t)b_pw * kNC + m * kH + j_pw];
      }
    }
  }
}

}  // namespace

extern "C" void kernel_launch(void* const* d_in, const int* in_sizes, int n_in,
                              void* d_out, int out_size, void* d_ws,
                              size_t ws_size, hipStream_t stream) {
  const int* marks = (const int*)d_in[0];
  const float* ts = (const float*)d_in[1];
  const float* latent = (const float*)d_in[2];
  const float* emb = (const float*)d_in[3];
  const float* Wc = (const float*)d_in[4];
  const float* bc = (const float*)d_in[5];
  const float* Wi = (const float*)d_in[6];
  const float* bi = (const float*)d_in[7];
  float* out = (float*)d_out;

  char* ws = (char*)d_ws;
  float* emb_part = (float*)(ws + 0);                 // 1,835,008 B
  float* lat_part = (float*)(ws + 1835008);           //   458,752 B
  float* dt       = (float*)(ws + 2293760);           //    65,536 B
  float* cd0      = (float*)(ws + 2359296);           //    65,536 B
  float* cb0      = (float*)(ws + 2424832);           //    65,536 B
  unsigned int* hdtag = (unsigned int*)(ws + 2490368); //  262,144 B

  hawkes_setup<<<286, 256, 0, stream>>>(ts, latent, emb, Wc, bc, Wi, bi, out,
                                        emb_part, lat_part, dt, cd0, cb0,
                                        hdtag);
  hawkes_seq<<<256, 512, 0, stream>>>(marks, Wc, out, emb_part, lat_part, dt,
                                      cd0, cb0, hdtag);
}